// Round 1
// baseline (101.867 us; speedup 1.0000x reference)
//
#include <hip/hip_runtime.h>
#include <math.h>

#define B_TOTAL 2048
#define I_TOTAL 2048
#define O_TOTAL 2048
#define KW 64
#define NIN 6
#define BLOCK 256
#define TILE_B 16
#define OBLOCKS (O_TOTAL / BLOCK)   /* 8   */
#define BBLOCKS (B_TOTAL / TILE_B)  /* 128 */

// Prep: sigw = sigmoid(table); mapping (int64 OR int32, auto-detected) -> int32 m32.
// Runs fresh every launch (ws is re-poisoned by the harness).
__global__ void prep_kernel(const float* __restrict__ table,
                            const unsigned int* __restrict__ map_raw,
                            float* __restrict__ sigw,
                            int* __restrict__ m32)
{
    int idx = blockIdx.x * blockDim.x + threadIdx.x;
    const int total = O_TOTAL * KW;   // 131072 sigmoids
    if (idx < total) {
        float v = table[idx];
        sigw[idx] = 1.0f / (1.0f + __expf(-v));
    }
    const int nmap = O_TOTAL * NIN;   // 12288 indices
    if (idx < nmap) {
        // int64 little-endian with values < 2048 => high words (odd u32) are 0.
        // int32 random values in [0,2048) => odd words nonzero w.p. 1 - 2^-44.
        bool is64 = ((map_raw[1] | map_raw[3] | map_raw[5] | map_raw[7]) == 0u);
        int val = is64 ? (int)map_raw[2 * idx] : (int)map_raw[idx];
        m32[idx] = val;
    }
}

// Main: lanes over o (coalesced weights/mapping/out), loop over TILE_B b's.
// Per (b,o): 6 gathered x loads + 126-FMA multilinear contraction.
__global__ __launch_bounds__(BLOCK) void lut_main(
    const float* __restrict__ x,
    const float* __restrict__ sigw,
    const int*   __restrict__ m32,
    float*       __restrict__ out)
{
    const int o  = blockIdx.y * BLOCK + threadIdx.x;
    const int b0 = blockIdx.x * TILE_B;

    // 64 sigmoid weights for this o -> registers (persist across b loop)
    float ww[KW];
    const float4* wp = (const float4*)(sigw + (size_t)o * KW);
    #pragma unroll
    for (int i = 0; i < KW / 4; ++i) {
        float4 v = wp[i];
        ww[4*i+0] = v.x; ww[4*i+1] = v.y; ww[4*i+2] = v.z; ww[4*i+3] = v.w;
    }

    int m[NIN];
    #pragma unroll
    for (int i = 0; i < NIN; ++i) m[i] = m32[o * NIN + i];

    for (int ib = 0; ib < TILE_B; ++ib) {
        const float* xr = x + (size_t)(b0 + ib) * I_TOTAL;
        float xv[NIN];
        #pragma unroll
        for (int i = 0; i < NIN; ++i) xv[i] = xr[m[i]];  // uniform base + lane offset

        // contract weights against bits, high bit (x5, stride 32) first
        float t[32];
        #pragma unroll
        for (int j = 0; j < 32; ++j) t[j] = fmaf(xv[5], ww[j+32] - ww[j], ww[j]);
        #pragma unroll
        for (int j = 0; j < 16; ++j) t[j] = fmaf(xv[4], t[j+16] - t[j], t[j]);
        #pragma unroll
        for (int j = 0; j < 8;  ++j) t[j] = fmaf(xv[3], t[j+8]  - t[j], t[j]);
        #pragma unroll
        for (int j = 0; j < 4;  ++j) t[j] = fmaf(xv[2], t[j+4]  - t[j], t[j]);
        #pragma unroll
        for (int j = 0; j < 2;  ++j) t[j] = fmaf(xv[1], t[j+2]  - t[j], t[j]);
        float res = fmaf(xv[0], t[1] - t[0], t[0]);

        out[(size_t)(b0 + ib) * O_TOTAL + o] = res;  // lanes over o: coalesced
    }
}

extern "C" void kernel_launch(void* const* d_in, const int* in_sizes, int n_in,
                              void* d_out, int out_size, void* d_ws, size_t ws_size,
                              hipStream_t stream)
{
    const float*        x       = (const float*)d_in[0];
    const float*        table   = (const float*)d_in[1];
    const unsigned int* map_raw = (const unsigned int*)d_in[2];
    float* out  = (float*)d_out;
    float* sigw = (float*)d_ws;                                  // 512 KB
    int*   m32  = (int*)((char*)d_ws + (size_t)O_TOTAL * KW * sizeof(float)); // +48 KB

    prep_kernel<<<(O_TOTAL * KW) / BLOCK, BLOCK, 0, stream>>>(table, map_raw, sigw, m32);

    dim3 grid(BBLOCKS, OBLOCKS);
    lut_main<<<grid, dim3(BLOCK), 0, stream>>>(x, sigw, m32, out);
}

// Round 2
// 84.286 us; speedup vs baseline: 1.2086x; 1.2086x over previous
//
#include <hip/hip_runtime.h>
#include <math.h>

#define B_TOTAL 2048
#define I_TOTAL 2048
#define O_TOTAL 2048
#define KW 64
#define NIN 6
#define BLOCK 256
#define TILE_B 16          // b-rows per block
#define CH 4               // rows staged in LDS at a time (32 KB)
#define BBLOCKS (B_TOTAL / TILE_B)  /* 128 */
#define OBLOCKS (O_TOTAL / BLOCK)   /* 8   */

// Prep: wT[k][o] layout (coalesced per-lane weight loads in main).
//   k in [0,32): wT = sigmoid(table[o][k])                (the "lo" value)
//   k in [32,64): wT = sigmoid(table[o][k]) - sigmoid(table[o][k-32])  (the diff)
// Also mapping -> transposed int32 m32T[i][o] (int64/int32 auto-detected).
__global__ void prep_kernel(const float* __restrict__ table,
                            const unsigned int* __restrict__ map_raw,
                            float* __restrict__ wT,
                            int* __restrict__ m32T)
{
    int idx = blockIdx.x * blockDim.x + threadIdx.x;   // 0 .. O*KW-1
    int o = idx >> 6, k = idx & 63;
    float s = 1.0f / (1.0f + __expf(-table[idx]));
    float v;
    if (k >= 32) {
        float s0 = 1.0f / (1.0f + __expf(-table[idx - 32]));
        v = s - s0;
    } else {
        v = s;
    }
    wT[k * O_TOTAL + o] = v;

    if (idx < O_TOTAL * NIN) {
        // int64 little-endian with values < 2048 => odd u32 words are all 0.
        bool is64 = ((map_raw[1] | map_raw[3] | map_raw[5] | map_raw[7]) == 0u);
        int val = is64 ? (int)map_raw[2 * idx] : (int)map_raw[idx];
        int oo = idx / NIN, ii = idx - oo * NIN;
        m32T[ii * O_TOTAL + oo] = val;
    }
}

// Main: lanes over o (coalesced weights/mapping/out). x rows staged in LDS so
// the 6-way random gather is ds_read (random banks ~2-way: near-free) instead
// of a 64-address VMEM gather (~64 cy/instr address-issue).
__global__ __launch_bounds__(BLOCK) void lut_main(
    const float* __restrict__ x,
    const float* __restrict__ wT,
    const int*   __restrict__ m32T,
    float*       __restrict__ out)
{
    __shared__ float xs[CH * I_TOTAL];   // 32 KB -> LDS allows 5 blocks/CU

    const int o  = blockIdx.y * BLOCK + threadIdx.x;
    const int b0 = blockIdx.x * TILE_B;

    // 64 weights (lo[0:32] + diff[32:64]) -> registers, coalesced loads
    float ww[KW];
    #pragma unroll
    for (int k = 0; k < KW; ++k) ww[k] = wT[k * O_TOTAL + o];

    int m[NIN];
    #pragma unroll
    for (int i = 0; i < NIN; ++i) m[i] = m32T[i * O_TOTAL + o];

    #pragma unroll
    for (int c = 0; c < TILE_B / CH; ++c) {
        __syncthreads();
        // stage CH rows cooperatively: 2048 float4 by 256 threads = 8 each
        const float4* src = (const float4*)(x + (size_t)(b0 + c * CH) * I_TOTAL);
        float4* dst = (float4*)xs;
        #pragma unroll
        for (int t = 0; t < (CH * I_TOTAL / 4) / BLOCK; ++t)
            dst[t * BLOCK + threadIdx.x] = src[t * BLOCK + threadIdx.x];
        __syncthreads();

        #pragma unroll
        for (int cr = 0; cr < CH; ++cr) {
            const float* xr = xs + cr * I_TOTAL;
            float xv[NIN];
            #pragma unroll
            for (int i = 0; i < NIN; ++i) xv[i] = xr[m[i]];   // LDS gather

            // multilinear contraction, level 0 uses precomputed diffs
            float t[32];
            #pragma unroll
            for (int j = 0; j < 32; ++j) t[j] = fmaf(xv[5], ww[j + 32], ww[j]);
            #pragma unroll
            for (int j = 0; j < 16; ++j) t[j] = fmaf(xv[4], t[j + 16] - t[j], t[j]);
            #pragma unroll
            for (int j = 0; j < 8;  ++j) t[j] = fmaf(xv[3], t[j + 8]  - t[j], t[j]);
            #pragma unroll
            for (int j = 0; j < 4;  ++j) t[j] = fmaf(xv[2], t[j + 4]  - t[j], t[j]);
            #pragma unroll
            for (int j = 0; j < 2;  ++j) t[j] = fmaf(xv[1], t[j + 2]  - t[j], t[j]);
            float res = fmaf(xv[0], t[1] - t[0], t[0]);

            out[(size_t)(b0 + c * CH + cr) * O_TOTAL + o] = res;  // coalesced
        }
    }
}

extern "C" void kernel_launch(void* const* d_in, const int* in_sizes, int n_in,
                              void* d_out, int out_size, void* d_ws, size_t ws_size,
                              hipStream_t stream)
{
    const float*        x       = (const float*)d_in[0];
    const float*        table   = (const float*)d_in[1];
    const unsigned int* map_raw = (const unsigned int*)d_in[2];
    float* out  = (float*)d_out;
    float* wT   = (float*)d_ws;                                        // 512 KB
    int*   m32T = (int*)((char*)d_ws + (size_t)O_TOTAL * KW * sizeof(float)); // +48 KB

    prep_kernel<<<(O_TOTAL * KW) / BLOCK, BLOCK, 0, stream>>>(table, map_raw, wT, m32T);

    dim3 grid(BBLOCKS, OBLOCKS);
    lut_main<<<grid, dim3(BLOCK), 0, stream>>>(x, wT, m32T, out);
}